// Round 6
// baseline (70.875 us; speedup 1.0000x reference)
//
#include <hip/hip_runtime.h>
#include <math.h>

// RegistrationRender: 6 views x (src,tgt) x 256x256 max-of-gaussians render.
// SINGLE fused SCATTER kernel: block = (image vh, 8-row strip). 384 blocks.
//
// Math: v = pv_k * exp(-5000*d2)  ->  max_k v = exp2(-C * min_k (dx^2+dy^2+pen_k)),
//   C = 5000*log2(e), pen_k = -log2(pv_k)/C >= 0  (pv=0 -> +1e26 -> contributes 0).
// Culling: pairs with |dx|>RCUT or |dy|>RCUT (RCUT=0.084) contribute
//   < exp(-5000*0.084^2) ~ 5e-16 -> droppable far below tolerance.
// SCATTER vs gather: a splat covers only a 22x22-px disc -> ~11.4M point-pixel
//   pairs total vs ~156M for 64x16-tile gather (round 3/5's 28 us kernel).
//   Each block: (A) rotate all 8192 pts (coalesced float4) for depth min/max —
//   fmin/fmax exact & order-independent -> bitwise-identical across blocks;
//   (B) filter own half to strip y-window +-RCUT into LDS queue; (C) scatter:
//   thread=(row,cand) pairs, ~22-col loop, atomicMin on u32 bits of e (e>=0 ->
//   bit-monotone -> exact float min, order-independent -> deterministic);
//   (D) exp2 epilogue. Untouched px = +inf -> exp2(-inf)=0 -> out=-1 (matches
//   reference within 5e-16).
// fb rows padded to 257 words: unpadded stride-256 puts all 8 rows' col-c
//   atomics in one bank (8-way conflict).

#define WIMG 256
#define HALF 4096
#define CLOG2 7213.475204444817f          // 5000 * log2(e)
#define INV_CLOG2 1.3862943611198906e-4f  // ln(2)/5000
#define RCUT 0.084f
#define QCAP 1024
#define FBPAD 257

// Rotation matrices: exact f32 casts of numpy float64 cos/sin values.
static __device__ __constant__ float RMAT[6][9] = {
  { 1.f, 0.f, 0.f,   0.f, 1.f, 0.f,   0.f, 0.f, 1.f },
  { 6.123233995736766e-17f, 0.f, 1.f,  0.f, 1.f, 0.f,  -1.f, 0.f, 6.123233995736766e-17f },
  { -1.f, 0.f, 1.2246467991473532e-16f, 0.f, 1.f, 0.f, -1.2246467991473532e-16f, 0.f, -1.f },
  { -1.8369701987210297e-16f, 0.f, -1.f, 0.f, 1.f, 0.f,  1.f, 0.f, -1.8369701987210297e-16f },
  { 1.f, 0.f, 0.f,  0.f, 6.123233995736766e-17f, -1.f,  0.f, 1.f, 6.123233995736766e-17f },
  { 1.f, 0.f, 0.f,  0.f, -1.8369701987210297e-16f, 1.f, 0.f, -1.f, -1.8369701987210297e-16f },
};

__global__ __launch_bounds__(256) void fused_render(const float* __restrict__ src,
                                                    const float* __restrict__ tgt,
                                                    float* __restrict__ out) {
  __shared__ unsigned fbu[8 * FBPAD];    // framebuffer: u32 bits of e (f32 >= 0)
  __shared__ float4 cq[QCAP];            // candidate queue {x, y, pen, 0}
  __shared__ float smin[4], smax[4];
  __shared__ int s_n;

  const int b = blockIdx.x;              // 384 = 12 images * 32 strips
  const int vh = b >> 5;
  const int strip = ((b & 31) + 13 * vh) & 31;   // load-balance swizzle
  const int v = vh >> 1, h = vh & 1;
  const int row0 = strip << 3;
  const int tid = threadIdx.x;
  const int lane = tid & 63, w = tid >> 6;

  const float* R = RMAT[v];
  const float r00 = R[0], r01 = R[1], r02 = R[2];
  const float r10 = R[3], r11 = R[4], r12 = R[5];
  const float r20 = R[6], r21 = R[7], r22 = R[8];

  // framebuffer init (+inf) and queue counter — before the phase-A barrier
  for (int i = tid; i < 8 * FBPAD; i += 256) fbu[i] = 0x7F800000u;
  if (tid == 0) s_n = 0;

  const float4* own4 = (const float4*)(h ? tgt : src);
  const float4* oth4 = (const float4*)(h ? src : tgt);

  // ---- phase A: coalesced loads; z min/max over ALL 8192 points.
  float zmin = 3.0e38f, zmax = -3.0e38f;
  float4 q[12];
#pragma unroll
  for (int j = 0; j < 4; ++j) {
    const int t = tid + 256 * j;
    const float4 a = oth4[3 * t], bq = oth4[3 * t + 1], c = oth4[3 * t + 2];
    const float z0 = r20 * a.x  + r21 * a.y  + r22 * a.z;
    const float z1 = r20 * a.w  + r21 * bq.x + r22 * bq.y;
    const float z2 = r20 * bq.z + r21 * bq.w + r22 * c.x;
    const float z3 = r20 * c.y  + r21 * c.z  + r22 * c.w;
    zmin = fminf(zmin, fminf(fminf(z0, z1), fminf(z2, z3)));
    zmax = fmaxf(zmax, fmaxf(fmaxf(z0, z1), fmaxf(z2, z3)));
  }
#pragma unroll
  for (int j = 0; j < 4; ++j) {
    const int t = tid + 256 * j;
    q[3 * j]     = own4[3 * t];
    q[3 * j + 1] = own4[3 * t + 1];
    q[3 * j + 2] = own4[3 * t + 2];
    const float4 a = q[3 * j], bq = q[3 * j + 1], c = q[3 * j + 2];
    const float z0 = r20 * a.x  + r21 * a.y  + r22 * a.z;
    const float z1 = r20 * a.w  + r21 * bq.x + r22 * bq.y;
    const float z2 = r20 * bq.z + r21 * bq.w + r22 * c.x;
    const float z3 = r20 * c.y  + r21 * c.z  + r22 * c.w;
    zmin = fminf(zmin, fminf(fminf(z0, z1), fminf(z2, z3)));
    zmax = fmaxf(zmax, fmaxf(fmaxf(z0, z1), fmaxf(z2, z3)));
  }
#pragma unroll
  for (int off = 32; off > 0; off >>= 1) {
    zmin = fminf(zmin, __shfl_down(zmin, off));
    zmax = fmaxf(zmax, __shfl_down(zmax, off));
  }
  if (lane == 0) { smin[w] = zmin; smax[w] = zmax; }
  __syncthreads();                       // covers fb init, s_n, smin/smax
  const float dmin = fminf(fminf(smin[0], smin[1]), fminf(smin[2], smin[3]));
  const float dmax = fmaxf(fmaxf(smax[0], smax[1]), fmaxf(smax[2], smax[3]));
  const float range = dmax - dmin;

  // ---- phase B: rotate own 16 points from regs, strip-window filter into queue
  const float wy0 = (row0 - 127.5f) * 0.0078125f - RCUT;
  const float wy1 = (row0 + 7 - 127.5f) * 0.0078125f + RCUT;
#pragma unroll
  for (int j = 0; j < 4; ++j) {
    const float4 a = q[3 * j], bq = q[3 * j + 1], c = q[3 * j + 2];
    const float P[4][3] = { { a.x, a.y, a.z }, { a.w, bq.x, bq.y },
                            { bq.z, bq.w, c.x }, { c.y, c.z, c.w } };
#pragma unroll
    for (int e = 0; e < 4; ++e) {
      const float x = r00 * P[e][0] + r01 * P[e][1] + r02 * P[e][2];
      const float y = r10 * P[e][0] + r11 * P[e][1] + r12 * P[e][2];
      if (y >= wy0 && y <= wy1 && fabsf(x) <= 1.081f) {
        const float z = r20 * P[e][0] + r21 * P[e][1] + r22 * P[e][2];
        const float pv = 1.0f - (z - dmin) / range;    // same op order as ref
        const float pen = (pv > 0.f) ? (-log2f(pv) * INV_CLOG2) : 1.0e26f;
        const int idx = atomicAdd(&s_n, 1);
        if (idx < QCAP) cq[idx] = make_float4(x, y, pen, 0.f);
      }
    }
  }
  __syncthreads();
  const int nc = min(s_n, QCAP);

  // ---- phase C: scatter. thread = (row r, cand slot); ~22-col loop per cand.
  const int r = tid >> 5;                // 0..7: lanes sharing a row get
  const int ci = tid & 31;               //   scattered cols -> few bank conflicts
  const float py = (row0 + r - 127.5f) * 0.0078125f;
  unsigned* fr = fbu + r * FBPAD;
  for (int base = 0; base < nc; base += 32) {
    const int k = base + ci;
    if (k < nc) {
      const float4 P = cq[k];
      const float dy = P.y - py;
      if (fabsf(dy) <= RCUT) {
        const float dy2 = fmaf(dy, dy, P.z);
        int c0 = (int)floorf(fmaf(P.x - RCUT, 128.0f, 127.5f));   // conservative
        int c1 = (int)ceilf (fmaf(P.x + RCUT, 128.0f, 127.5f));
        c0 = max(c0, 0); c1 = min(c1, 255);
        float px = fmaf((float)c0, 0.0078125f, -0.99609375f);     // exact grid
        for (int c = c0; c <= c1; ++c) {
          const float dx = P.x - px;
          const float e = fmaf(dx, dx, dy2);
          atomicMin(&fr[c], __float_as_uint(e));   // e>=0: u32 min == f32 min
          px += 0.0078125f;
        }
      }
    }
  }
  __syncthreads();

  // ---- phase D: exp2 epilogue, coalesced store (8 px/thread)
  float* o = out + (vh * WIMG + row0) * WIMG;
#pragma unroll
  for (int i = 0; i < 8; ++i) {
    const float e = __uint_as_float(fbu[i * FBPAD + tid]);
    o[i * WIMG + tid] = 2.0f * exp2f(-CLOG2 * e) - 1.0f;   // +inf -> -1
  }
}

extern "C" void kernel_launch(void* const* d_in, const int* in_sizes, int n_in,
                              void* d_out, int out_size, void* d_ws, size_t ws_size,
                              hipStream_t stream) {
  const float* src = (const float*)d_in[0];   // (4096,3) f32
  const float* tgt = (const float*)d_in[1];   // (4096,3) f32
  float* out = (float*)d_out;                 // (6,2,256,256) f32
  (void)d_ws; (void)ws_size;
  fused_render<<<384, 256, 0, stream>>>(src, tgt, out);
}